// Round 6
// baseline (105.215 us; speedup 1.0000x reference)
//
#include <hip/hip_runtime.h>
#include <hip/hip_fp16.h>

#define N 2048
#define ONW 4096
#define LUT_ENTRIES 12288
#define SMEM_BYTES (LUT_ENTRIES * 8)   // 98304 B fp16 LUT only

typedef _Float16 half4v __attribute__((ext_vector_type(4)));
typedef float fvec4 __attribute__((ext_vector_type(4)));

__device__ __forceinline__ int reflect(int i) {
    i = i < 0 ? -i : i;
    return i >= N ? 2 * N - 2 - i : i;
}

__global__ __launch_bounds__(1024, 4) void hdblut_kernel(
    const int* __restrict__ img, const float4* __restrict__ w4,
    float* __restrict__ out)
{
    extern __shared__ unsigned char smem[];
    half4v* lut = (half4v*)smem;

    const int tx = threadIdx.x;            // 0..63  (one wave = one ty row)
    const int ty = threadIdx.y;            // 0..15
    const int tid = ty * 64 + tx;
    const int x0 = (int)(blockIdx.x & 15) * 128;       // 16 x-strips
    const int y0 = (int)(blockIdx.x >> 4) * 128;       // 16 y-bands

    // 1) fp32 -> fp16 LUT into LDS (once per block)
    #pragma unroll
    for (int i = 0; i < 12; ++i) {
        int j = tid + i * 1024;
        float4 v = w4[j];
        half4v h;
        h.x = (_Float16)v.x; h.y = (_Float16)v.y;
        h.z = (_Float16)v.z; h.w = (_Float16)v.w;
        lut[j] = h;
    }
    __syncthreads();   // the only barrier

    const int bo[3][2] = {{0, 1}, {1, 1}, {1, 2}};
    const int co[3][2] = {{0, 2}, {2, 2}, {2, 1}};
    const float s = 1.0f / 3.0f;
    fvec4* o4 = (fvec4*)out;

    const int gj0 = x0 + 2 * tx - 2;                 // leftmost neighborhood col
    const bool fastx = (gj0 >= 0) && (gj0 + 5 < N);  // no col reflection needed

    #pragma unroll 1
    for (int t = 0; t < 4; ++t) {
        const int py0 = y0 + t * 32 + 2 * ty;        // top pixel row of patch

        // 2) 6x6 neighborhood from global (L1-served) + pre-shifted copy
        int n[6][6], m[6][6];
        #pragma unroll
        for (int r = 0; r < 6; ++r) {
            const int rb = reflect(py0 - 2 + r) * N;
            if (fastx) {
                int2 a = *(const int2*)&img[rb + gj0];
                int2 b = *(const int2*)&img[rb + gj0 + 2];
                int2 c = *(const int2*)&img[rb + gj0 + 4];
                n[r][0] = a.x; n[r][1] = a.y;
                n[r][2] = b.x; n[r][3] = b.y;
                n[r][4] = c.x; n[r][5] = c.y;
            } else {
                #pragma unroll
                for (int c = 0; c < 6; ++c)
                    n[r][c] = img[rb + reflect(gj0 + c)];
            }
            #pragma unroll
            for (int c = 0; c < 6; ++c) m[r][c] = n[r][c] << 4;
        }

        float acc[2][2][4];
        #pragma unroll
        for (int i = 0; i < 2; ++i)
            #pragma unroll
            for (int j = 0; j < 2; ++j)
                #pragma unroll
                for (int c = 0; c < 4; ++c) acc[i][j][c] = 0.f;

        // 3) per pixel-pair: 24 indices -> 24 gathers in flight -> consume
        #pragma unroll
        for (int pi = 0; pi < 2; ++pi) {
            int idx[24];
            #pragma unroll
            for (int pj = 0; pj < 2; ++pj) {
                const int abase = n[2 + pi][2 + pj] << 8;
                #pragma unroll
                for (int r = 0; r < 4; ++r) {
                    #pragma unroll
                    for (int k = 0; k < 3; ++k) {
                        const int bp = bo[k][0], bq = bo[k][1];
                        const int cp = co[k][0], cq = co[k][1];
                        const int bdi = (r == 0) ? bp : (r == 1) ? bq : (r == 2) ? -bp : -bq;
                        const int bdj = (r == 0) ? bq : (r == 1) ? -bp : (r == 2) ? -bq : bp;
                        const int cdi = (r == 0) ? cp : (r == 1) ? cq : (r == 2) ? -cp : -cq;
                        const int cdj = (r == 0) ? cq : (r == 1) ? -cp : (r == 2) ? -cq : cp;
                        idx[pj * 12 + r * 3 + k] =
                            ((k << 12) + abase) + m[pi + 2 + bdi][pj + 2 + bdj]
                                                + n[pi + 2 + cdi][pj + 2 + cdj];
                    }
                }
            }
            half4v v[24];
            #pragma unroll
            for (int i = 0; i < 24; ++i) v[i] = lut[idx[i]];

            #pragma unroll
            for (int pj = 0; pj < 2; ++pj) {
                float* o = acc[pi][pj];
                #pragma unroll
                for (int r = 0; r < 4; ++r) {
                    half4v S = v[pj * 12 + 3 * r] + v[pj * 12 + 3 * r + 1]
                                                  + v[pj * 12 + 3 * r + 2];
                    const float x = (float)S.x, y = (float)S.y;
                    const float z = (float)S.z, w = (float)S.w;
                    if (r == 0)      { o[0] += x; o[1] += y; o[2] += z; o[3] += w; }
                    else if (r == 1) { o[0] += z; o[1] += x; o[2] += w; o[3] += y; }
                    else if (r == 2) { o[0] += w; o[1] += z; o[2] += y; o[3] += x; }
                    else             { o[0] += y; o[1] += w; o[2] += x; o[3] += z; }
                }
            }
        }

        // 4) wave-contiguous stores (1 KiB per wave per row)
        const int ox = (x0 + 2 * tx) * 2;
        fvec4 v0 = {acc[0][0][0] * s, acc[0][0][1] * s, acc[0][1][0] * s, acc[0][1][1] * s};
        fvec4 v1 = {acc[0][0][2] * s, acc[0][0][3] * s, acc[0][1][2] * s, acc[0][1][3] * s};
        fvec4 v2 = {acc[1][0][0] * s, acc[1][0][1] * s, acc[1][1][0] * s, acc[1][1][1] * s};
        fvec4 v3 = {acc[1][0][2] * s, acc[1][0][3] * s, acc[1][1][2] * s, acc[1][1][3] * s};
        o4[((2 * py0 + 0) * ONW + ox) >> 2] = v0;
        o4[((2 * py0 + 1) * ONW + ox) >> 2] = v1;
        o4[((2 * py0 + 2) * ONW + ox) >> 2] = v2;
        o4[((2 * py0 + 3) * ONW + ox) >> 2] = v3;
    }
}

extern "C" void kernel_launch(void* const* d_in, const int* in_sizes, int n_in,
                              void* d_out, int out_size, void* d_ws, size_t ws_size,
                              hipStream_t stream)
{
    const int* img = (const int*)d_in[0];
    const float4* w4 = (const float4*)d_in[1];
    float* out = (float*)d_out;
    (void)hipFuncSetAttribute(reinterpret_cast<const void*>(hdblut_kernel),
                              hipFuncAttributeMaxDynamicSharedMemorySize, SMEM_BYTES);
    hdblut_kernel<<<dim3(256), dim3(64, 16), SMEM_BYTES, stream>>>(img, w4, out);
}

// Round 7
// 94.376 us; speedup vs baseline: 1.1149x; 1.1149x over previous
//
#include <hip/hip_runtime.h>
#include <hip/hip_fp16.h>

#define N 2048
#define ONW 4096
#define TW 128                        // tile width (pixels)
#define TH 32                         // tile height (pixels)
#define HW 132                        // halo tile width (ints)
#define HH 36                         // halo tile height
#define HELEMS (HW * HH)              // 4752
#define LUT_ENTRIES 12288
#define LUT_BYTES (LUT_ENTRIES * 8)   // 98304
#define SMEM_BYTES (LUT_BYTES + 2 * HELEMS * 4)  // 136320 <= 160K

typedef _Float16 half4v __attribute__((ext_vector_type(4)));
typedef float fvec4 __attribute__((ext_vector_type(4)));

__device__ __forceinline__ int reflect(int i) {
    i = i < 0 ? -i : i;
    return i >= N ? 2 * N - 2 - i : i;
}

__global__ __launch_bounds__(1024, 4) void hdblut_kernel(
    const int* __restrict__ img, const float4* __restrict__ w4,
    float* __restrict__ out)
{
    extern __shared__ unsigned char smem[];
    half4v* lut = (half4v*)smem;
    int* bufs = (int*)(smem + LUT_BYTES);

    const int tx = threadIdx.x;            // 0..63  (one wave = one ty row)
    const int ty = threadIdx.y;            // 0..15
    const int tid = ty * 64 + tx;
    const int x0 = (int)(blockIdx.x & 15) * TW;        // 16 x-strips
    const int y0 = (int)(blockIdx.x >> 4) * (TH * 4);  // 16 y-bands, 4 tiles each

    // 1) fp32 -> fp16 LUT into LDS (once per block)
    #pragma unroll
    for (int i = 0; i < 12; ++i) {
        int j = tid + i * 1024;
        float4 v = w4[j];
        half4v h;
        h.x = (_Float16)v.x; h.y = (_Float16)v.y;
        h.z = (_Float16)v.z; h.w = (_Float16)v.w;
        lut[j] = h;
    }

    // 2) tile 0 halo load (direct to LDS)
    for (int e = tid; e < HELEMS; e += 1024) {
        int rr = e / HW, cc = e - rr * HW;
        bufs[e] = img[reflect(y0 + rr - 2) * N + reflect(x0 + cc - 2)];
    }
    __syncthreads();

    const int bo[3][2] = {{0, 1}, {1, 1}, {1, 2}};
    const int co[3][2] = {{0, 2}, {2, 2}, {2, 1}};
    const float s = 1.0f / 3.0f;
    fvec4* o4 = (fvec4*)out;

    int pre[5];
    #pragma unroll 1
    for (int t = 0; t < 4; ++t) {
        int* cur = bufs + (t & 1) * HELEMS;
        int* nxt = bufs + ((t + 1) & 1) * HELEMS;

        // prefetch next tile into registers (latency hidden by compute)
        if (t < 3) {
            const int yb = y0 + (t + 1) * TH;
            #pragma unroll
            for (int u = 0; u < 5; ++u) {
                int e = tid + u * 1024;
                if (e < HELEMS) {
                    int rr = e / HW, cc = e - rr * HW;
                    pre[u] = img[reflect(yb + rr - 2) * N + reflect(x0 + cc - 2)];
                }
            }
        }

        // 3) 6x6 neighborhood for this thread's 2x2 pixel patch
        int n[6][6];
        {
            const int r0 = 2 * ty, c0 = 2 * tx;
            #pragma unroll
            for (int r = 0; r < 6; ++r)
                #pragma unroll
                for (int j = 0; j < 3; ++j) {
                    int2 t2 = *(const int2*)&cur[(r0 + r) * HW + c0 + 2 * j];
                    n[r][2 * j] = t2.x; n[r][2 * j + 1] = t2.y;
                }
        }

        float acc[2][2][4];
        #pragma unroll
        for (int i = 0; i < 2; ++i)
            #pragma unroll
            for (int j = 0; j < 2; ++j)
                #pragma unroll
                for (int c = 0; c < 4; ++c) acc[i][j][c] = 0.f;

        // 4) per pixel-pair: 24 indices -> 24 gathers in flight -> consume
        #pragma unroll
        for (int pi = 0; pi < 2; ++pi) {
            int idx[24];
            #pragma unroll
            for (int pj = 0; pj < 2; ++pj) {
                const int a8 = n[2 + pi][2 + pj] << 8;
                #pragma unroll
                for (int r = 0; r < 4; ++r) {
                    #pragma unroll
                    for (int k = 0; k < 3; ++k) {
                        const int bp = bo[k][0], bq = bo[k][1];
                        const int cp = co[k][0], cq = co[k][1];
                        const int bdi = (r == 0) ? bp : (r == 1) ? bq : (r == 2) ? -bp : -bq;
                        const int bdj = (r == 0) ? bq : (r == 1) ? -bp : (r == 2) ? -bq : bp;
                        const int cdi = (r == 0) ? cp : (r == 1) ? cq : (r == 2) ? -cp : -cq;
                        const int cdj = (r == 0) ? cq : (r == 1) ? -cp : (r == 2) ? -cq : cp;
                        const int bv = n[pi + 2 + bdi][pj + 2 + bdj];
                        const int cv = n[pi + 2 + cdi][pj + 2 + cdj];
                        idx[pj * 12 + r * 3 + k] = (k * 4096 + a8) + (bv * 16 + cv);
                    }
                }
            }
            half4v v[24];
            #pragma unroll
            for (int i = 0; i < 24; ++i) v[i] = lut[idx[i]];
            // pin the 24 ds_read_b64 into one contiguous issue group
            __builtin_amdgcn_sched_group_barrier(0x100, 24, 0);

            #pragma unroll
            for (int pj = 0; pj < 2; ++pj) {
                float* o = acc[pi][pj];
                #pragma unroll
                for (int r = 0; r < 4; ++r) {
                    half4v S = v[pj * 12 + 3 * r] + v[pj * 12 + 3 * r + 1]
                                                  + v[pj * 12 + 3 * r + 2];
                    const float x = (float)S.x, y = (float)S.y;
                    const float z = (float)S.z, w = (float)S.w;
                    if (r == 0)      { o[0] += x; o[1] += y; o[2] += z; o[3] += w; }
                    else if (r == 1) { o[0] += z; o[1] += x; o[2] += w; o[3] += y; }
                    else if (r == 2) { o[0] += w; o[1] += z; o[2] += y; o[3] += x; }
                    else             { o[0] += y; o[1] += w; o[2] += x; o[3] += z; }
                }
            }
        }

        // 5) wave-contiguous stores (1 KiB per wave per row)
        const int py = y0 + t * TH + 2 * ty;
        const int ox = (x0 + 2 * tx) * 2;
        {
            fvec4 v0 = {acc[0][0][0] * s, acc[0][0][1] * s, acc[0][1][0] * s, acc[0][1][1] * s};
            fvec4 v1 = {acc[0][0][2] * s, acc[0][0][3] * s, acc[0][1][2] * s, acc[0][1][3] * s};
            fvec4 v2 = {acc[1][0][0] * s, acc[1][0][1] * s, acc[1][1][0] * s, acc[1][1][1] * s};
            fvec4 v3 = {acc[1][0][2] * s, acc[1][0][3] * s, acc[1][1][2] * s, acc[1][1][3] * s};
            o4[((2 * py + 0) * ONW + ox) >> 2] = v0;
            o4[((2 * py + 1) * ONW + ox) >> 2] = v1;
            o4[((2 * py + 2) * ONW + ox) >> 2] = v2;
            o4[((2 * py + 3) * ONW + ox) >> 2] = v3;
        }

        // commit prefetched tile to the other LDS buffer
        if (t < 3) {
            #pragma unroll
            for (int u = 0; u < 5; ++u) {
                int e = tid + u * 1024;
                if (e < HELEMS) nxt[e] = pre[u];
            }
        }
        __syncthreads();
    }
}

extern "C" void kernel_launch(void* const* d_in, const int* in_sizes, int n_in,
                              void* d_out, int out_size, void* d_ws, size_t ws_size,
                              hipStream_t stream)
{
    const int* img = (const int*)d_in[0];
    const float4* w4 = (const float4*)d_in[1];
    float* out = (float*)d_out;
    (void)hipFuncSetAttribute(reinterpret_cast<const void*>(hdblut_kernel),
                              hipFuncAttributeMaxDynamicSharedMemorySize, SMEM_BYTES);
    hdblut_kernel<<<dim3(256), dim3(64, 16), SMEM_BYTES, stream>>>(img, w4, out);
}